// Round 8
// baseline (214.503 us; speedup 1.0000x reference)
//
#include <hip/hip_runtime.h>
#include <stdint.h>

typedef __bf16 bf16x8 __attribute__((ext_vector_type(8)));
typedef __bf16 bf16x2 __attribute__((ext_vector_type(2)));
typedef float  f32x4  __attribute__((ext_vector_type(4)));
typedef short  s16x8  __attribute__((ext_vector_type(8)));

__device__ inline unsigned short f2b(float f) {
  unsigned int u = __builtin_bit_cast(unsigned int, f);
  u += 0x7FFFu + ((u >> 16) & 1u);
  return (unsigned short)(u >> 16);
}
__device__ inline float b2f(unsigned short h) {
  unsigned int u = ((unsigned int)h) << 16;
  return __builtin_bit_cast(float, u);
}
// native pack: compiler emits v_cvt_pk_bf16_f32
__device__ inline unsigned int pkcvt(float a, float b) {
  bf16x2 t;
  t[0] = (__bf16)a;
  t[1] = (__bf16)b;
  return __builtin_bit_cast(unsigned int, t);
}
__device__ inline void gload_lds16(const void* g, void* l) {
  __builtin_amdgcn_global_load_lds(
      (const __attribute__((address_space(1))) unsigned int*)g,
      (__attribute__((address_space(3))) unsigned int*)l, 16, 0, 0);
}

// ---------------- elementwise f32 -> bf16 ----------------
__global__ void k_cvt_bf16(const float* __restrict__ in, unsigned short* __restrict__ out, int n4) {
  int i = blockIdx.x * blockDim.x + threadIdx.x;
  if (i < n4) {
    float4 v = ((const float4*)in)[i];
    ushort4 o;
    o.x = f2b(v.x); o.y = f2b(v.y); o.z = f2b(v.z); o.w = f2b(v.w);
    ((ushort4*)out)[i] = o;
  }
}

// ---------------- transpose f32 -> bf16 [N][K]; z=0: Wq|Wk|Wv concat, z=1: Wo ----------------
__global__ void k_transpose(const float* __restrict__ Wq, const float* __restrict__ Wk,
                            const float* __restrict__ Wv, const float* __restrict__ Wo,
                            unsigned short* __restrict__ dstQKV, unsigned short* __restrict__ dstO) {
  __shared__ float tile[32][33];
  int n0 = blockIdx.x * 32;
  int k0 = blockIdx.y * 32;
  const float* src; int ldn, noff, K;
  unsigned short* dst;
  if (blockIdx.z == 0) {
    K = 2048; dst = dstQKV;
    if (n0 < 2048)       { src = Wq; ldn = 2048; noff = n0; }
    else if (n0 < 2176)  { src = Wk; ldn = 128;  noff = n0 - 2048; }
    else                 { src = Wv; ldn = 128;  noff = n0 - 2176; }
  } else {
    if (n0 >= 2048) return;
    K = 2048; dst = dstO;
    src = Wo; ldn = 2048; noff = n0;
  }
  int tx = threadIdx.x & 31, ty = threadIdx.x >> 5;
  for (int yy = ty; yy < 32; yy += 8)
    tile[yy][tx] = src[(size_t)(k0 + yy) * ldn + noff + tx];
  __syncthreads();
  for (int yy = ty; yy < 32; yy += 8)
    dst[(size_t)(n0 + yy) * K + k0 + tx] = f2b(tile[tx][yy]);
}

// ---------------- bias concat [2304] ----------------
__global__ void k_bias_concat(const float* __restrict__ bq, const float* __restrict__ bk,
                              const float* __restrict__ bv, float* __restrict__ dst) {
  int i = blockIdx.x * 256 + threadIdx.x;
  if (i < 2304) dst[i] = (i < 2048) ? bq[i] : (i < 2176 ? bk[i - 2048] : bv[i - 2176]);
}

// ---------------- bf16 GEMM: C = A * Bt^T + bias ----------------
template<int OUT_BF16>
__global__ __launch_bounds__(256)
void k_gemm_lds(const unsigned short* __restrict__ A, const unsigned short* __restrict__ Bt,
                const float* __restrict__ bias, void* __restrict__ Cout,
                int M, int N, int K) {
  __shared__ unsigned short As[2][4096];   // [buf][128*32] linear
  __shared__ unsigned short Bs[2][4096];
  const int tid  = threadIdx.x;
  const int lane = tid & 63, wid = tid >> 6;
  const int lr = lane & 15, lk = lane >> 4;
  const int wr = wid >> 1,  wc = wid & 1;
  const int mb = blockIdx.y * 128, nb = blockIdx.x * 128;

  const int srow = tid >> 2, scb = (tid & 3) * 8;
  const size_t gA = (size_t)(mb + srow) * K + scb;
  const size_t gB = (size_t)(nb + srow) * K + scb;
  const int ldso = wid * 512;

  f32x4 acc[4][4];
  #pragma unroll
  for (int i = 0; i < 4; ++i)
    #pragma unroll
    for (int j = 0; j < 4; ++j) acc[i][j] = (f32x4){0.f, 0.f, 0.f, 0.f};

  auto stage = [&](int buf, int kt) {
    const size_t ko = (size_t)kt * 32;
    gload_lds16(A  + gA + ko,                  &As[buf][ldso]);
    gload_lds16(A  + gA + 64 * (size_t)K + ko, &As[buf][2048 + ldso]);
    gload_lds16(Bt + gB + ko,                  &Bs[buf][ldso]);
    gload_lds16(Bt + gB + 64 * (size_t)K + ko, &Bs[buf][2048 + ldso]);
  };

  const int ktn = K >> 5;
  stage(0, 0);

  int cur = 0;
  #pragma unroll 1
  for (int kt = 0; kt < ktn; ++kt) {
    if (kt + 1 < ktn) {
      stage(cur ^ 1, kt + 1);
      asm volatile("s_waitcnt vmcnt(4)" ::: "memory");   // drain current tile only
    } else {
      asm volatile("s_waitcnt vmcnt(0)" ::: "memory");
    }
    __builtin_amdgcn_sched_barrier(0);
    __builtin_amdgcn_s_barrier();        // tile data visible to all waves
    bf16x8 af[4], bfv[4];
    #pragma unroll
    for (int m = 0; m < 4; ++m)
      af[m]  = *(const bf16x8*)&As[cur][(wr * 64 + m * 16 + lr) * 32 + lk * 8];
    #pragma unroll
    for (int n = 0; n < 4; ++n)
      bfv[n] = *(const bf16x8*)&Bs[cur][(wc * 64 + n * 16 + lr) * 32 + lk * 8];
    #pragma unroll
    for (int m = 0; m < 4; ++m)
      #pragma unroll
      for (int n = 0; n < 4; ++n)
        acc[m][n] = __builtin_amdgcn_mfma_f32_16x16x32_bf16(af[m], bfv[n], acc[m][n], 0, 0, 0);
    __builtin_amdgcn_s_barrier();        // all reads done before next overwrite
    cur ^= 1;
  }

  const int r0 = mb + wr * 64, c0 = nb + wc * 64;
  #pragma unroll
  for (int m = 0; m < 4; ++m) {
    #pragma unroll
    for (int n = 0; n < 4; ++n) {
      int col = c0 + n * 16 + lr;
      float bb = bias[col];
      #pragma unroll
      for (int r = 0; r < 4; ++r) {
        int row = r0 + m * 16 + lk * 4 + r;
        float v = acc[m][n][r] + bb;
        if (OUT_BF16) ((unsigned short*)Cout)[(size_t)row * N + col] = f2b(v);
        else          ((float*)Cout)[(size_t)row * N + col] = v;
      }
    }
  }
}

// ---------------- RoPE (q heads + k); q pre-scaled by 1/sqrt(D) ----------------
__global__ void k_rope(const unsigned short* __restrict__ qkv,
                       unsigned short* __restrict__ qr,
                       unsigned short* __restrict__ kr,
                       int S, int H) {
  int R = blockIdx.x * 4 + (threadIdx.x >> 6);
  int lane = threadIdx.x & 63;
  int per_b = S * (H + 1);
  int b = R / per_b;
  int rem = R - b * per_b;
  int s = rem / (H + 1);
  int j = rem - s * (H + 1);
  const unsigned short* src = qkv + (size_t)(b * S + s) * 2304 + (j < H ? j * 128 : 2048);
  float x1 = b2f(src[lane]);
  float x2 = b2f(src[lane + 64]);
  float invf = expf(-(float)lane * (9.210340371976184f / 64.0f));
  float ang = (float)s * invf;
  float c = cosf(ang), sn = sinf(ang);
  float o1 = x1 * c - x2 * sn;
  float o2 = x1 * sn + x2 * c;
  unsigned short* dst;
  if (j < H) {
    const float scale = 0.08838834764831845f;  // fold 1/sqrt(128) into q
    o1 *= scale; o2 *= scale;
    dst = qr + ((size_t)(b * H + j) * S + s) * 128;
  } else {
    dst = kr + ((size_t)(b * S) + s) * 128;
  }
  dst[lane]      = f2b(o1);
  dst[lane + 64] = f2b(o2);
}

// ---------------- V transpose ----------------
__global__ void k_vtrans(const unsigned short* __restrict__ qkv,
                         unsigned short* __restrict__ vt, int S) {
  __shared__ unsigned short tile[32][33];
  int b = blockIdx.z;
  int s0 = blockIdx.x * 32, d0 = blockIdx.y * 32;
  int tx = threadIdx.x & 31, ty = threadIdx.x >> 5;
  for (int yy = ty; yy < 32; yy += 8)
    tile[yy][tx] = qkv[(size_t)(b * S + s0 + yy) * 2304 + 2176 + d0 + tx];
  __syncthreads();
  for (int yy = ty; yy < 32; yy += 8)
    vt[((size_t)b * 128 + d0 + yy) * S + s0 + tx] = tile[tx][yy];
}

// ---------------- causal flash attention ----------------
// MQA: 2 heads per block (8 waves = 2 heads x 4 waves) share staged K/V.
// Swapped QK^T with PERMUTED K rows: kf[m] loads keys base_m + (lr>>2)*8 + (lr&3)
// (base_m = (m>>1)*32 + (m&1)*4), so each lane's 16 scores are exactly keys
// {lk*8+0..7} u {32+lk*8+0..7}: the PV A-fragment is the lane's own cvt_pk
// pairs -- no P LDS, no shuffles. No-max softmax (q pre-scaled in RoPE).
// K/V via global_load_lds w16, double-buffered, swizzle swz=(row&3)|((row>>1)&4),
// counted vmcnt. Grid 32x8x2; qt = z ? x : 31-x pairs heavy+light per CU.
__global__ __launch_bounds__(512, 4)
void k_attn(const unsigned short* __restrict__ qr,  // [B][H][S][128]
            const unsigned short* __restrict__ kr,  // [B][S][128]
            const unsigned short* __restrict__ vt,  // [B][128][S]
            unsigned short* __restrict__ attn_out,  // [B][S][2048]
            int S, int H) {
  const int b = blockIdx.z;
  const int nqt = gridDim.x;
  const int qt = blockIdx.z ? (int)blockIdx.x : (nqt - 1 - (int)blockIdx.x);
  const int qb0 = qt * 64;
  const int tid = threadIdx.x, wid = tid >> 6, lane = tid & 63;
  const int lr = lane & 15, lk = lane >> 4;
  const int hh = wid >> 2, w4 = wid & 3;
  const int h = blockIdx.y * 2 + hh;
  const int qw = qb0 + w4 * 16;

  __shared__ unsigned short Kt[2][64 * 128];   // 16KB each
  __shared__ unsigned short Vt[2][128 * 64];   // 16KB each

  const char* kbyte = (const char*)(kr + (size_t)b * S * 128);
  const char* vbyte = (const char*)(vt + (size_t)b * 128 * S);
  const size_t vrow_bytes = (size_t)S * 2;

  const unsigned short* qptr = qr + ((size_t)(b * H + h) * S + (qw + lr)) * 128;
  bf16x8 aq[4];
  #pragma unroll
  for (int kk = 0; kk < 4; ++kk) aq[kk] = *(const bf16x8*)(qptr + kk * 32 + lk * 8);

  f32x4 accO[8];
  #pragma unroll
  for (int t = 0; t < 8; ++t) accO[t] = (f32x4){0.f, 0.f, 0.f, 0.f};
  float lsum = 0.f;

  const int vsw = ((lr & 3) | ((lr >> 1) & 4)) << 4;

  auto stage = [&](int buf, int kb) {
    const char* kg = kbyte + (size_t)kb * 256;
    #pragma unroll
    for (int r = 0; r < 2; ++r) {
      int row = (tid >> 4) + r * 32;
      int sw = ((row & 3) | ((row >> 1) & 4)) << 4;
      const char* src = kg + row * 256 + (((tid & 15) << 4) ^ sw);
      gload_lds16(src, (void*)((char*)&Kt[buf][0] + (wid * 4 + r * 32) * 256));
    }
    const char* vg = vbyte + (size_t)kb * 2;
    #pragma unroll
    for (int r = 0; r < 2; ++r) {
      int d = (tid >> 3) + r * 64;
      int sw = ((d & 3) | ((d >> 1) & 4)) << 4;
      const char* src = vg + (size_t)d * vrow_bytes + (((tid & 7) << 4) ^ sw);
      gload_lds16(src, (void*)((char*)&Vt[buf][0] + (wid * 8 + r * 64) * 128));
    }
  };

  int cur = 0;
  stage(0, 0);

  #pragma unroll 1
  for (int kb = 0; kb <= qb0; kb += 64) {
    if (kb + 64 <= qb0) {
      stage(cur ^ 1, kb + 64);
      asm volatile("s_waitcnt vmcnt(4)" ::: "memory");   // drain current tile only
    } else {
      asm volatile("s_waitcnt vmcnt(0)" ::: "memory");
    }
    __builtin_amdgcn_sched_barrier(0);
    __builtin_amdgcn_s_barrier();        // tile data visible
    const bool diag = (kb == qb0);
    const unsigned short* Kc = &Kt[cur][0];
    const unsigned short* Vc = &Vt[cur][0];

    // ---- QK^T (swapped, permuted K rows)
    bf16x8 kf[4][4];
    #pragma unroll
    for (int m = 0; m < 4; ++m) {
      const int row = ((m >> 1) << 5) + ((m & 1) << 2) + ((lr >> 2) << 3) + (lr & 3);
      const int sw = ((row & 3) | ((row >> 1) & 4)) << 4;
      const char* kl = (const char*)Kc + row * 256;
      #pragma unroll
      for (int kk = 0; kk < 4; ++kk)
        kf[m][kk] = *(const bf16x8*)(kl + ((kk * 64 + lk * 16) ^ sw));
    }
    f32x4 s4[4];
    #pragma unroll
    for (int m = 0; m < 4; ++m) s4[m] = (f32x4){0.f, 0.f, 0.f, 0.f};
    __builtin_amdgcn_s_setprio(1);
    #pragma unroll
    for (int kk = 0; kk < 4; ++kk)
      #pragma unroll
      for (int m = 0; m < 4; ++m)
        s4[m] = __builtin_amdgcn_mfma_f32_16x16x32_bf16(kf[m][kk], aq[kk], s4[m], 0, 0, 0);
    __builtin_amdgcn_s_setprio(0);

    // ---- exp, diag mask, per-lane denominator; pack P lane-locally
    uint2 pk[4];
    #pragma unroll
    for (int m = 0; m < 4; ++m) {
      const int kbase = ((m >> 1) << 5) + ((m & 1) << 2) + lk * 8;
      float p[4];
      #pragma unroll
      for (int r = 0; r < 4; ++r) {
        float v = __expf(s4[m][r]);
        if (diag && (kbase + r) > (w4 * 16 + lr)) v = 0.f;
        p[r] = v;
        lsum += v;
      }
      pk[m].x = pkcvt(p[0], p[1]);
      pk[m].y = pkcvt(p[2], p[3]);
    }
    uint4 ua, ub;
    ua.x = pk[0].x; ua.y = pk[0].y; ua.z = pk[1].x; ua.w = pk[1].y;
    ub.x = pk[2].x; ub.y = pk[2].y; ub.z = pk[3].x; ub.w = pk[3].y;
    bf16x8 pa0 = __builtin_bit_cast(bf16x8, ua);
    bf16x8 pa1 = __builtin_bit_cast(bf16x8, ub);

    // ---- PV from staged V
    __builtin_amdgcn_s_setprio(1);
    #pragma unroll
    for (int t = 0; t < 8; ++t) {
      const char* vl = (const char*)(Vc + (t * 16 + lr) * 64);
      bf16x8 bv0 = *(const bf16x8*)(vl + ((lk * 16) ^ vsw));
      accO[t] = __builtin_amdgcn_mfma_f32_16x16x32_bf16(pa0, bv0, accO[t], 0, 0, 0);
      bf16x8 bv1 = *(const bf16x8*)(vl + ((64 + lk * 16) ^ vsw));
      accO[t] = __builtin_amdgcn_mfma_f32_16x16x32_bf16(pa1, bv1, accO[t], 0, 0, 0);
    }
    __builtin_amdgcn_s_setprio(0);
    __builtin_amdgcn_s_barrier();        // all reads of cur done
    cur ^= 1;
  }

  // ---- epilogue
  lsum += __shfl_xor(lsum, 16);
  lsum += __shfl_xor(lsum, 32);
  float rl[4];
  #pragma unroll
  for (int r = 0; r < 4; ++r) rl[r] = 1.0f / __shfl(lsum, lk * 4 + r);
  #pragma unroll
  for (int t = 0; t < 8; ++t) {
    #pragma unroll
    for (int r = 0; r < 4; ++r) {
      int srow = qw + lk * 4 + r;
      float o = accO[t][r] * rl[r];
      attn_out[((size_t)(b * S) + srow) * 2048 + h * 128 + t * 16 + lr] = f2b(o);
    }
  }
}

// ---------------- launch ----------------
extern "C" void kernel_launch(void* const* d_in, const int* in_sizes, int n_in,
                              void* d_out, int out_size, void* d_ws, size_t ws_size,
                              hipStream_t stream) {
  const float* x  = (const float*)d_in[0];
  const float* Wq = (const float*)d_in[1];
  const float* bq = (const float*)d_in[2];
  const float* Wk = (const float*)d_in[3];
  const float* bk = (const float*)d_in[4];
  const float* Wv = (const float*)d_in[5];
  const float* bv = (const float*)d_in[6];
  const float* Wo = (const float*)d_in[7];
  const float* bo = (const float*)d_in[8];

  const int B = 2, S = 2048, E = 2048, H = 16, D = 128;
  const int M = B * S;             // 4096
  const int Nqkv = H * D + 2 * D;  // 2304

  char* w = (char*)d_ws;
  unsigned short* xb    = (unsigned short*)w;                              // 16,777,216 B
  unsigned short* WqkvT = (unsigned short*)(w + 16777216);                 //  9,437,184 B
  unsigned short* qkv   = (unsigned short*)(w + 16777216 + 9437184);       // 18,874,368 B
  unsigned short* qr    = (unsigned short*)(w + 16777216 + 9437184 + 18874368); // 16,777,216 B
  unsigned short* kr    = qr + (size_t)B * H * S * D;
  unsigned short* vtb   = kr + (size_t)B * S * D;
  float*          cbias = (float*)(vtb + (size_t)B * S * D);
  unsigned short* WoT   = (unsigned short*)(cbias + 4096);
  unsigned short* attn_out = xb;     // alias: xb dead after gemm1

  k_cvt_bf16<<<dim3((M * E / 4) / 256), 256, 0, stream>>>(x, xb, M * E / 4);
  k_transpose<<<dim3(Nqkv / 32, E / 32, 2), 256, 0, stream>>>(Wq, Wk, Wv, Wo, WqkvT, WoT);
  k_bias_concat<<<dim3(9), 256, 0, stream>>>(bq, bk, bv, cbias);
  k_gemm_lds<1><<<dim3(Nqkv / 128, M / 128), 256, 0, stream>>>(xb, WqkvT, cbias, (void*)qkv, M, Nqkv, E);
  k_rope<<<dim3(B * S * (H + 1) / 4), 256, 0, stream>>>(qkv, qr, kr, S, H);
  k_vtrans<<<dim3(S / 32, D / 32, B), 256, 0, stream>>>(qkv, vtb, S);
  k_attn<<<dim3(S / 64, H / 2, B), 512, 0, stream>>>(qr, kr, vtb, attn_out, S, H);
  k_gemm_lds<0><<<dim3(E / 128, M / 128), 256, 0, stream>>>(attn_out, WoT, bo, (void*)d_out, M, E, H * D);
}